// Round 1
// baseline (805.804 us; speedup 1.0000x reference)
//
#include <hip/hip_runtime.h>

#define NB    16
#define NCH   512
#define NCOL  16384
#define NPTS  4096

// ---------------------------------------------------------------------------
// Phase 1: z[b][i] = max_c y[b][c][i], encoded as 64-bit descending sort key:
//   key = (sortable_uint(z) << 32) | (16383 - i)
// sortable_uint: order-preserving float->uint map. Descending sort on key
// gives (value desc, index asc) — matches lax.top_k tie-breaking.
// ---------------------------------------------------------------------------
__global__ void max_key_kernel(const float* __restrict__ y,
                               unsigned long long* __restrict__ keys) {
    unsigned i = blockIdx.x * 256u + threadIdx.x;   // column 0..16383
    unsigned b = blockIdx.y;                        // batch
    const float* p = y + ((size_t)b << 23) + i;     // b*512*16384
    float m = p[0];
    #pragma unroll 8
    for (int c = 1; c < NCH; ++c) m = fmaxf(m, p[(size_t)c << 14]);
    unsigned u = __float_as_uint(m);
    unsigned s = (u & 0x80000000u) ? ~u : (u | 0x80000000u);
    keys[((size_t)b << 14) + i] =
        ((unsigned long long)s << 32) | (unsigned long long)(16383u - i);
}

// ---------------------------------------------------------------------------
// Phase 2: full bitonic sort (descending) of 16384 keys in LDS, one
// workgroup per batch. Writes the top-4096 indices.
// ---------------------------------------------------------------------------
__global__ __launch_bounds__(1024) void topk_sort_kernel(
        const unsigned long long* __restrict__ keys, int* __restrict__ idx) {
    __shared__ unsigned long long sk[NCOL];   // 128 KiB
    unsigned tid = threadIdx.x;
    unsigned b   = blockIdx.x;
    const unsigned long long* gk = keys + ((size_t)b << 14);

    for (unsigned i = tid; i < NCOL; i += 1024) sk[i] = gk[i];
    __syncthreads();

    for (unsigned k = 2; k <= NCOL; k <<= 1) {
        for (unsigned j = k >> 1; j > 0; j >>= 1) {
            for (unsigned i = tid; i < NCOL; i += 1024) {
                unsigned ixj = i ^ j;
                if (ixj > i) {
                    unsigned long long a = sk[i];
                    unsigned long long c2 = sk[ixj];
                    // descending final order: (i&k)==0 segment sorts desc
                    bool sw = ((i & k) == 0) ? (a < c2) : (a > c2);
                    if (sw) { sk[i] = c2; sk[ixj] = a; }
                }
            }
            __syncthreads();
        }
    }

    for (unsigned j = tid; j < NPTS; j += 1024) {
        idx[(b << 12) + j] =
            (int)(16383u - (unsigned)(sk[j] & 0xFFFFFFFFull));
    }
}

// ---------------------------------------------------------------------------
// Phase 3: gather x -> top_k_xyz  (16,3,4096)
// ---------------------------------------------------------------------------
__global__ void gather_xyz_kernel(const float* __restrict__ x,
                                  const int* __restrict__ idx,
                                  float* __restrict__ out) {
    unsigned o  = blockIdx.x * 256u + threadIdx.x;  // within batch, 0..12287
    unsigned b  = blockIdx.y;
    unsigned ch = o >> 12;          // 0..2
    unsigned j  = o & 4095u;
    int i = idx[(b << 12) | j];
    out[((size_t)b * 3u + ch) * 4096u + j] =
        x[(((size_t)b * 3u + ch) << 14) + (unsigned)i];
}

// ---------------------------------------------------------------------------
// Phase 4: gather y -> top_k_points  (16,512,4096)
// ---------------------------------------------------------------------------
__global__ void gather_points_kernel(const float* __restrict__ y,
                                     const int* __restrict__ idx,
                                     float* __restrict__ out) {
    unsigned o = blockIdx.x * 256u + threadIdx.x;   // within batch, 0..2097151
    unsigned b = blockIdx.y;
    unsigned c = o >> 12;           // 0..511
    unsigned j = o & 4095u;
    int i = idx[(b << 12) | j];
    out[(((size_t)b << 9) + c) * 4096u + j] =
        y[((((size_t)b << 9) + c) << 14) + (unsigned)i];
}

extern "C" void kernel_launch(void* const* d_in, const int* in_sizes, int n_in,
                              void* d_out, int out_size, void* d_ws, size_t ws_size,
                              hipStream_t stream) {
    const float* x = (const float*)d_in[0];
    const float* y = (const float*)d_in[1];
    float* out = (float*)d_out;

    unsigned long long* keys = (unsigned long long*)d_ws;                 // 2 MiB
    int* idx = (int*)((char*)d_ws + (size_t)NB * NCOL * sizeof(unsigned long long));

    max_key_kernel<<<dim3(NCOL / 256, NB), 256, 0, stream>>>(y, keys);
    topk_sort_kernel<<<NB, 1024, 0, stream>>>(keys, idx);
    gather_xyz_kernel<<<dim3(3 * NPTS / 256, NB), 256, 0, stream>>>(x, idx, out);
    gather_points_kernel<<<dim3((NCH * NPTS) / 256, NB), 256, 0, stream>>>(
        y, idx, out + (size_t)NB * 3 * NPTS);
}

// Round 2
// 607.854 us; speedup vs baseline: 1.3257x; 1.3257x over previous
//
#include <hip/hip_runtime.h>

#define NB    16
#define NCH   512
#define NCOL  16384
#define NPTS  4096

// ---------------------------------------------------------------------------
// Phase 1: z[b][i] = max_c y[b][c][i], encoded as 64-bit descending sort key:
//   key = (sortable_uint(z) << 32) | (16383 - i)
// Unique keys -> total order; descending sort == (value desc, index asc),
// matching lax.top_k tie-breaking. float4-vectorized: thread owns 4 columns.
// ---------------------------------------------------------------------------
__global__ void max_key_kernel(const float* __restrict__ y,
                               unsigned long long* __restrict__ keys) {
    unsigned t = blockIdx.x * 256u + threadIdx.x;   // 0..4095 per batch
    unsigned b = blockIdx.y;
    unsigned i = t << 2;                            // column group base
    const float* p = y + ((size_t)b << 23) + i;
    float4 m = *(const float4*)p;
    #pragma unroll 4
    for (int c = 1; c < NCH; ++c) {
        float4 v = *(const float4*)(p + ((size_t)c << 14));
        m.x = fmaxf(m.x, v.x); m.y = fmaxf(m.y, v.y);
        m.z = fmaxf(m.z, v.z); m.w = fmaxf(m.w, v.w);
    }
    unsigned long long* kp = keys + ((size_t)b << 14) + i;
    float mv[4] = {m.x, m.y, m.z, m.w};
    #pragma unroll
    for (int q = 0; q < 4; ++q) {
        unsigned u = __float_as_uint(mv[q]);
        unsigned s = (u & 0x80000000u) ? ~u : (u | 0x80000000u);
        kp[q] = ((unsigned long long)s << 32) |
                (unsigned long long)(16383u - (i + q));
    }
}

// ---------------------------------------------------------------------------
// Phase 2a: sort each 4096-chunk descending (bitonic, in LDS). 64 blocks.
// ---------------------------------------------------------------------------
__global__ __launch_bounds__(1024) void chunk_sort_kernel(
        unsigned long long* __restrict__ keys) {
    __shared__ unsigned long long sk[4096];   // 32 KiB
    unsigned tid = threadIdx.x;
    unsigned b = blockIdx.x >> 2, ch = blockIdx.x & 3;
    unsigned long long* gk = keys + ((size_t)b << 14) + ((size_t)ch << 12);

    for (unsigned i = tid; i < 4096; i += 1024) sk[i] = gk[i];
    __syncthreads();
    for (unsigned k = 2; k <= 4096; k <<= 1) {
        for (unsigned j = k >> 1; j > 0; j >>= 1) {
            for (unsigned i = tid; i < 4096; i += 1024) {
                unsigned ixj = i ^ j;
                if (ixj > i) {
                    unsigned long long a = sk[i], c2 = sk[ixj];
                    bool sw = ((i & k) == 0) ? (a < c2) : (a > c2);
                    if (sw) { sk[i] = c2; sk[ixj] = a; }
                }
            }
            __syncthreads();
        }
    }
    for (unsigned i = tid; i < 4096; i += 1024) gk[i] = sk[i];
}

// ---------------------------------------------------------------------------
// Phase 2b: merge 4 sorted-desc chunks -> exact top-4096 sorted desc.
// Top-n of two desc lists A,B: C[i]=max(A[i],B[n-1-i]) (bitonic valley),
// then 12-pass bitonic merge. One block per batch.
// ---------------------------------------------------------------------------
__global__ __launch_bounds__(1024) void merge_kernel(
        const unsigned long long* __restrict__ keys, int* __restrict__ idx) {
    __shared__ unsigned long long sk[8192];   // 64 KiB
    unsigned tid = threadIdx.x, b = blockIdx.x;
    const unsigned long long* gk = keys + ((size_t)b << 14);

    for (unsigned i = tid; i < 4096; i += 1024) {
        unsigned long long a0 = gk[i],        b0 = gk[4096 + (4095 - i)];
        unsigned long long a1 = gk[8192 + i], b1 = gk[12288 + (4095 - i)];
        sk[i]        = a0 > b0 ? a0 : b0;
        sk[4096 + i] = a1 > b1 ? a1 : b1;
    }
    __syncthreads();
    // bitonic merge each 4096-half to descending (j < 4096 keeps halves apart)
    for (unsigned j = 2048; j > 0; j >>= 1) {
        for (unsigned i = tid; i < 8192; i += 1024) {
            unsigned ixj = i ^ j;
            if (ixj > i) {
                unsigned long long a = sk[i], c2 = sk[ixj];
                if (a < c2) { sk[i] = c2; sk[ixj] = a; }
            }
        }
        __syncthreads();
    }
    // top-4096 of the two sorted halves -> bitonic valley in first half
    for (unsigned i = tid; i < 4096; i += 1024) {
        unsigned long long a = sk[i], c2 = sk[8191 - i];
        sk[i] = a > c2 ? a : c2;
    }
    __syncthreads();
    for (unsigned j = 2048; j > 0; j >>= 1) {
        for (unsigned i = tid; i < 4096; i += 1024) {
            unsigned ixj = i ^ j;
            if (ixj > i) {
                unsigned long long a = sk[i], c2 = sk[ixj];
                if (a < c2) { sk[i] = c2; sk[ixj] = a; }
            }
        }
        __syncthreads();
    }
    for (unsigned j = tid; j < NPTS; j += 1024)
        idx[(b << 12) + j] = (int)(16383u - (unsigned)(sk[j] & 0xFFFFFFFFull));
}

// ---------------------------------------------------------------------------
// Phase 3a: pos[b][i] = -1
// ---------------------------------------------------------------------------
__global__ void init_pos_kernel(int* __restrict__ pos) {
    pos[blockIdx.x * 256u + threadIdx.x] = -1;
}

// ---------------------------------------------------------------------------
// Phase 3b: pos[b][idx[b][j]] = j  (inverse permutation, unique idx)
// ---------------------------------------------------------------------------
__global__ void scatter_pos_kernel(const int* __restrict__ idx,
                                   int* __restrict__ pos) {
    unsigned j = blockIdx.x * 256u + threadIdx.x;   // 0..4095
    unsigned b = blockIdx.y;
    pos[(b << 14) + (unsigned)idx[(b << 12) + j]] = (int)j;
}

// ---------------------------------------------------------------------------
// Phase 4a: stream x coalesced, scatter-write selected cols. (16,3,4096)
// ---------------------------------------------------------------------------
__global__ void gather_xyz_kernel(const float* __restrict__ x,
                                  const int* __restrict__ pos,
                                  float* __restrict__ out) {
    unsigned o = blockIdx.x * 256u + threadIdx.x;   // c*4096 + t, c in 0..2
    unsigned b = blockIdx.y;
    unsigned c = o >> 12;
    unsigned t = (o & 4095u) << 2;
    float4 v = *(const float4*)(x + ((((size_t)b * 3u + c)) << 14) + t);
    int4  pv = *(const int4*)(pos + ((size_t)b << 14) + t);
    float* orow = out + ((size_t)b * 3u + c) * 4096u;
    if (pv.x >= 0) orow[pv.x] = v.x;
    if (pv.y >= 0) orow[pv.y] = v.y;
    if (pv.z >= 0) orow[pv.z] = v.z;
    if (pv.w >= 0) orow[pv.w] = v.w;
}

// ---------------------------------------------------------------------------
// Phase 4b: stream y coalesced, scatter-write selected cols. (16,512,4096)
// ---------------------------------------------------------------------------
__global__ void gather_points_kernel(const float* __restrict__ y,
                                     const int* __restrict__ pos,
                                     float* __restrict__ out) {
    unsigned o = blockIdx.x * 256u + threadIdx.x;   // c*4096 + t
    unsigned b = blockIdx.y;
    unsigned c = o >> 12;
    unsigned t = (o & 4095u) << 2;
    float4 v = *(const float4*)(y + ((((size_t)b << 9) + c) << 14) + t);
    int4  pv = *(const int4*)(pos + ((size_t)b << 14) + t);
    float* orow = out + (((size_t)b << 9) + c) * 4096u;
    if (pv.x >= 0) orow[pv.x] = v.x;
    if (pv.y >= 0) orow[pv.y] = v.y;
    if (pv.z >= 0) orow[pv.z] = v.z;
    if (pv.w >= 0) orow[pv.w] = v.w;
}

extern "C" void kernel_launch(void* const* d_in, const int* in_sizes, int n_in,
                              void* d_out, int out_size, void* d_ws, size_t ws_size,
                              hipStream_t stream) {
    const float* x = (const float*)d_in[0];
    const float* y = (const float*)d_in[1];
    float* out = (float*)d_out;

    char* ws = (char*)d_ws;
    unsigned long long* keys = (unsigned long long*)ws;          // 2 MiB
    int* idx = (int*)(ws + (size_t)NB * NCOL * 8);               // 256 KiB
    int* pos = (int*)(ws + (size_t)NB * NCOL * 8 + (size_t)NB * NPTS * 4); // 1 MiB

    max_key_kernel<<<dim3(NCOL / 4 / 256, NB), 256, 0, stream>>>(y, keys);
    chunk_sort_kernel<<<NB * 4, 1024, 0, stream>>>(keys);
    merge_kernel<<<NB, 1024, 0, stream>>>(keys, idx);
    init_pos_kernel<<<NB * NCOL / 256, 256, 0, stream>>>(pos);
    scatter_pos_kernel<<<dim3(NPTS / 256, NB), 256, 0, stream>>>(idx, pos);
    gather_xyz_kernel<<<dim3(3 * NPTS / 256, NB), 256, 0, stream>>>(x, pos, out);
    gather_points_kernel<<<dim3((NCH * NPTS) / 256, NB), 256, 0, stream>>>(
        y, pos, out + (size_t)NB * 3 * NPTS);
}

// Round 3
// 419.606 us; speedup vs baseline: 1.9204x; 1.4486x over previous
//
#include <hip/hip_runtime.h>

#define NB    16
#define NCH   512
#define NCOL  16384
#define NPTS  4096

// ---------------------------------------------------------------------------
// Phase 1: z[b][i] = max_c y[b][c][i], encoded as 64-bit descending sort key:
//   key = (sortable_uint(z) << 32) | (16383 - i)
// Unique keys -> total order; descending sort == (value desc, index asc),
// matching lax.top_k tie-breaking. float4-vectorized.
// ---------------------------------------------------------------------------
__global__ void max_key_kernel(const float* __restrict__ y,
                               unsigned long long* __restrict__ keys) {
    unsigned t = blockIdx.x * 256u + threadIdx.x;   // 0..4095 per batch
    unsigned b = blockIdx.y;
    unsigned i = t << 2;
    const float* p = y + ((size_t)b << 23) + i;
    float4 m = *(const float4*)p;
    #pragma unroll 4
    for (int c = 1; c < NCH; ++c) {
        float4 v = *(const float4*)(p + ((size_t)c << 14));
        m.x = fmaxf(m.x, v.x); m.y = fmaxf(m.y, v.y);
        m.z = fmaxf(m.z, v.z); m.w = fmaxf(m.w, v.w);
    }
    unsigned long long* kp = keys + ((size_t)b << 14) + i;
    float mv[4] = {m.x, m.y, m.z, m.w};
    #pragma unroll
    for (int q = 0; q < 4; ++q) {
        unsigned u = __float_as_uint(mv[q]);
        unsigned s = (u & 0x80000000u) ? ~u : (u | 0x80000000u);
        kp[q] = ((unsigned long long)s << 32) |
                (unsigned long long)(16383u - (i + q));
    }
}

// ---------------------------------------------------------------------------
// Phase 2a: sort each 4096-chunk descending (bitonic, in LDS). 64 blocks.
// ---------------------------------------------------------------------------
__global__ __launch_bounds__(1024) void chunk_sort_kernel(
        unsigned long long* __restrict__ keys) {
    __shared__ unsigned long long sk[4096];   // 32 KiB
    unsigned tid = threadIdx.x;
    unsigned b = blockIdx.x >> 2, ch = blockIdx.x & 3;
    unsigned long long* gk = keys + ((size_t)b << 14) + ((size_t)ch << 12);

    for (unsigned i = tid; i < 4096; i += 1024) sk[i] = gk[i];
    __syncthreads();
    for (unsigned k = 2; k <= 4096; k <<= 1) {
        for (unsigned j = k >> 1; j > 0; j >>= 1) {
            for (unsigned i = tid; i < 4096; i += 1024) {
                unsigned ixj = i ^ j;
                if (ixj > i) {
                    unsigned long long a = sk[i], c2 = sk[ixj];
                    bool sw = ((i & k) == 0) ? (a < c2) : (a > c2);
                    if (sw) { sk[i] = c2; sk[ixj] = a; }
                }
            }
            __syncthreads();
        }
    }
    for (unsigned i = tid; i < 4096; i += 1024) gk[i] = sk[i];
}

// ---------------------------------------------------------------------------
// Phase 2b: merge 4 sorted-desc chunks -> exact top-4096 sorted desc.
// Top-n of two desc lists A,B: C[i]=max(A[i],B[n-1-i]) (bitonic), then
// bitonic merge. One block per batch.
// ---------------------------------------------------------------------------
__global__ __launch_bounds__(1024) void merge_kernel(
        const unsigned long long* __restrict__ keys, int* __restrict__ idx) {
    __shared__ unsigned long long sk[8192];   // 64 KiB
    unsigned tid = threadIdx.x, b = blockIdx.x;
    const unsigned long long* gk = keys + ((size_t)b << 14);

    for (unsigned i = tid; i < 4096; i += 1024) {
        unsigned long long a0 = gk[i],        b0 = gk[4096 + (4095 - i)];
        unsigned long long a1 = gk[8192 + i], b1 = gk[12288 + (4095 - i)];
        sk[i]        = a0 > b0 ? a0 : b0;
        sk[4096 + i] = a1 > b1 ? a1 : b1;
    }
    __syncthreads();
    for (unsigned j = 2048; j > 0; j >>= 1) {
        for (unsigned i = tid; i < 8192; i += 1024) {
            unsigned ixj = i ^ j;
            if (ixj > i) {
                unsigned long long a = sk[i], c2 = sk[ixj];
                if (a < c2) { sk[i] = c2; sk[ixj] = a; }
            }
        }
        __syncthreads();
    }
    for (unsigned i = tid; i < 4096; i += 1024) {
        unsigned long long a = sk[i], c2 = sk[8191 - i];
        sk[i] = a > c2 ? a : c2;
    }
    __syncthreads();
    for (unsigned j = 2048; j > 0; j >>= 1) {
        for (unsigned i = tid; i < 4096; i += 1024) {
            unsigned ixj = i ^ j;
            if (ixj > i) {
                unsigned long long a = sk[i], c2 = sk[ixj];
                if (a < c2) { sk[i] = c2; sk[ixj] = a; }
            }
        }
        __syncthreads();
    }
    for (unsigned j = tid; j < NPTS; j += 1024)
        idx[(b << 12) + j] = (int)(16383u - (unsigned)(sk[j] & 0xFFFFFFFFull));
}

// ---------------------------------------------------------------------------
// Phase 3: LDS-staged row gather. One block per (b, c) source row:
// load 64 KiB row coalesced into LDS, gather to 16 KiB output row, write
// coalesced float4. Both global sides fully coalesced — no amplification.
// nch: 512 for y->points, 3 for x->xyz.
// ---------------------------------------------------------------------------
__global__ __launch_bounds__(256) void row_gather_kernel(
        const float* __restrict__ src, const int* __restrict__ idx,
        float* __restrict__ out, int nch) {
    __shared__ float row[NCOL];   // 64 KiB
    unsigned bc = blockIdx.x;             // b*nch + c
    unsigned b  = bc / (unsigned)nch;
    const float4* sv = (const float4*)(src + ((size_t)bc << 14));
    float4* rv = (float4*)row;
    #pragma unroll
    for (unsigned i = threadIdx.x; i < NCOL / 4; i += 256) rv[i] = sv[i];
    __syncthreads();
    const int* ib = idx + (b << 12);
    float* orow = out + (size_t)bc * NPTS;
    #pragma unroll
    for (unsigned j = threadIdx.x << 2; j < NPTS; j += 256 * 4) {
        int4 iv = *(const int4*)(ib + j);
        float4 ov;
        ov.x = row[iv.x]; ov.y = row[iv.y];
        ov.z = row[iv.z]; ov.w = row[iv.w];
        *(float4*)(orow + j) = ov;
    }
}

extern "C" void kernel_launch(void* const* d_in, const int* in_sizes, int n_in,
                              void* d_out, int out_size, void* d_ws, size_t ws_size,
                              hipStream_t stream) {
    const float* x = (const float*)d_in[0];
    const float* y = (const float*)d_in[1];
    float* out = (float*)d_out;

    char* ws = (char*)d_ws;
    unsigned long long* keys = (unsigned long long*)ws;          // 2 MiB
    int* idx = (int*)(ws + (size_t)NB * NCOL * 8);               // 256 KiB

    max_key_kernel<<<dim3(NCOL / 4 / 256, NB), 256, 0, stream>>>(y, keys);
    chunk_sort_kernel<<<NB * 4, 1024, 0, stream>>>(keys);
    merge_kernel<<<NB, 1024, 0, stream>>>(keys, idx);
    row_gather_kernel<<<NB * 3, 256, 0, stream>>>(x, idx, out, 3);
    row_gather_kernel<<<NB * NCH, 256, 0, stream>>>(
        y, idx, out + (size_t)NB * 3 * NPTS, NCH);
}

// Round 4
// 294.149 us; speedup vs baseline: 2.7394x; 1.4265x over previous
//
#include <hip/hip_runtime.h>

#define NB    16
#define NCH   512
#define NCOL  16384
#define NPTS  4096

// Barrier rule for bitonic passes with element mapping i ≡ tid (mod NT),
// NT = 1024 threads, wave = 64 lanes:
//   j >= 1024 : both pair elements owned by the SAME thread  -> no barrier
//   j <  64   : partner thread tid^j is in the SAME wave     -> no barrier
//               (per-wave LDS ops are program-ordered)
//   else      : cross-wave -> __syncthreads()
// Conservatively barrier when 32 <= j < 1024.
#define PASS_SYNC(j) do { if ((j) >= 32 && (j) < 1024) __syncthreads(); } while (0)

// ---------------------------------------------------------------------------
// Phase 1: z[b][i] = max_c y[b][c][i], encoded as 64-bit descending sort key:
//   key = (sortable_uint(z) << 32) | (16383 - i)
// Unique keys -> total order; descending sort == (value desc, index asc),
// matching lax.top_k tie-breaking.
// ---------------------------------------------------------------------------
__global__ void max_key_kernel(const float* __restrict__ y,
                               unsigned long long* __restrict__ keys) {
    unsigned t = blockIdx.x * 256u + threadIdx.x;   // 0..4095 per batch
    unsigned b = blockIdx.y;
    unsigned i = t << 2;
    const float* p = y + ((size_t)b << 23) + i;
    float4 m = *(const float4*)p;
    #pragma unroll 8
    for (int c = 1; c < NCH; ++c) {
        float4 v = *(const float4*)(p + ((size_t)c << 14));
        m.x = fmaxf(m.x, v.x); m.y = fmaxf(m.y, v.y);
        m.z = fmaxf(m.z, v.z); m.w = fmaxf(m.w, v.w);
    }
    unsigned long long* kp = keys + ((size_t)b << 14) + i;
    float mv[4] = {m.x, m.y, m.z, m.w};
    #pragma unroll
    for (int q = 0; q < 4; ++q) {
        unsigned u = __float_as_uint(mv[q]);
        unsigned s = (u & 0x80000000u) ? ~u : (u | 0x80000000u);
        kp[q] = ((unsigned long long)s << 32) |
                (unsigned long long)(16383u - (i + q));
    }
}

// ---------------------------------------------------------------------------
// Phase 2a: sort each 4096-chunk descending (bitonic, LDS). 64 blocks.
// ---------------------------------------------------------------------------
__global__ __launch_bounds__(1024) void chunk_sort_kernel(
        unsigned long long* __restrict__ keys) {
    __shared__ unsigned long long sk[4096];   // 32 KiB
    unsigned tid = threadIdx.x;
    unsigned b = blockIdx.x >> 2, ch = blockIdx.x & 3;
    unsigned long long* gk = keys + ((size_t)b << 14) + ((size_t)ch << 12);

    for (unsigned i = tid; i < 4096; i += 1024) sk[i] = gk[i];
    __syncthreads();
    for (unsigned k = 2; k <= 4096; k <<= 1) {
        for (unsigned j = k >> 1; j > 0; j >>= 1) {
            PASS_SYNC(j);
            for (unsigned i = tid; i < 4096; i += 1024) {
                unsigned ixj = i ^ j;
                if (ixj > i) {
                    unsigned long long a = sk[i], c2 = sk[ixj];
                    bool sw = ((i & k) == 0) ? (a < c2) : (a > c2);
                    if (sw) { sk[i] = c2; sk[ixj] = a; }
                }
            }
        }
    }
    __syncthreads();
    for (unsigned i = tid; i < 4096; i += 1024) gk[i] = sk[i];
}

// ---------------------------------------------------------------------------
// Phase 2b: merge 4 sorted-desc chunks -> exact top-4096 sorted desc.
// Top-n of two desc lists A,B: C[i]=max(A[i],B[n-1-i]) (bitonic), then
// bitonic merge. One block per batch.
// ---------------------------------------------------------------------------
__global__ __launch_bounds__(1024) void merge_kernel(
        const unsigned long long* __restrict__ keys, int* __restrict__ idx) {
    __shared__ unsigned long long sk[8192];   // 64 KiB
    unsigned tid = threadIdx.x, b = blockIdx.x;
    const unsigned long long* gk = keys + ((size_t)b << 14);

    for (unsigned i = tid; i < 4096; i += 1024) {
        unsigned long long a0 = gk[i],        b0 = gk[4096 + (4095 - i)];
        unsigned long long a1 = gk[8192 + i], b1 = gk[12288 + (4095 - i)];
        sk[i]        = a0 > b0 ? a0 : b0;
        sk[4096 + i] = a1 > b1 ? a1 : b1;
    }
    __syncthreads();
    // bitonic-merge each 4096-half to descending (j<4096 keeps halves apart)
    for (unsigned j = 2048; j > 0; j >>= 1) {
        PASS_SYNC(j);
        for (unsigned i = tid; i < 8192; i += 1024) {
            unsigned ixj = i ^ j;
            if (ixj > i) {
                unsigned long long a = sk[i], c2 = sk[ixj];
                if (a < c2) { sk[i] = c2; sk[ixj] = a; }
            }
        }
    }
    __syncthreads();
    // top-4096 of the two sorted halves -> bitonic valley in first half
    for (unsigned i = tid; i < 4096; i += 1024) {
        unsigned long long a = sk[i], c2 = sk[8191 - i];
        sk[i] = a > c2 ? a : c2;
    }
    __syncthreads();
    for (unsigned j = 2048; j > 0; j >>= 1) {
        PASS_SYNC(j);
        for (unsigned i = tid; i < 4096; i += 1024) {
            unsigned ixj = i ^ j;
            if (ixj > i) {
                unsigned long long a = sk[i], c2 = sk[ixj];
                if (a < c2) { sk[i] = c2; sk[ixj] = a; }
            }
        }
    }
    __syncthreads();
    for (unsigned j = tid; j < NPTS; j += 1024)
        idx[(b << 12) + j] = (int)(16383u - (unsigned)(sk[j] & 0xFFFFFFFFull));
}

// ---------------------------------------------------------------------------
// Phase 3: LDS-staged row gather, occupancy-fixed: 1024 threads + 64 KiB LDS
// -> 2 blocks/CU = 32 waves/CU. Both global sides fully coalesced.
// ---------------------------------------------------------------------------
__global__ __launch_bounds__(1024) void row_gather_kernel(
        const float* __restrict__ src, const int* __restrict__ idx,
        float* __restrict__ out, int nch) {
    __shared__ float row[NCOL];   // 64 KiB
    unsigned bc = blockIdx.x;             // b*nch + c
    unsigned b  = bc / (unsigned)nch;
    const float4* sv = (const float4*)(src + ((size_t)bc << 14));
    float4* rv = (float4*)row;
    #pragma unroll
    for (unsigned i = threadIdx.x; i < NCOL / 4; i += 1024) rv[i] = sv[i];
    __syncthreads();
    const int* ib = idx + (b << 12);
    float* orow = out + (size_t)bc * NPTS;
    unsigned j = threadIdx.x << 2;        // each thread: one float4 of output
    int4 iv = *(const int4*)(ib + j);
    float4 ov;
    ov.x = row[iv.x]; ov.y = row[iv.y];
    ov.z = row[iv.z]; ov.w = row[iv.w];
    *(float4*)(orow + j) = ov;
}

extern "C" void kernel_launch(void* const* d_in, const int* in_sizes, int n_in,
                              void* d_out, int out_size, void* d_ws, size_t ws_size,
                              hipStream_t stream) {
    const float* x = (const float*)d_in[0];
    const float* y = (const float*)d_in[1];
    float* out = (float*)d_out;

    char* ws = (char*)d_ws;
    unsigned long long* keys = (unsigned long long*)ws;          // 2 MiB
    int* idx = (int*)(ws + (size_t)NB * NCOL * 8);               // 256 KiB

    max_key_kernel<<<dim3(NCOL / 4 / 256, NB), 256, 0, stream>>>(y, keys);
    chunk_sort_kernel<<<NB * 4, 1024, 0, stream>>>(keys);
    merge_kernel<<<NB, 1024, 0, stream>>>(keys, idx);
    row_gather_kernel<<<NB * 3, 1024, 0, stream>>>(x, idx, out, 3);
    row_gather_kernel<<<NB * NCH, 1024, 0, stream>>>(
        y, idx, out + (size_t)NB * 3 * NPTS, NCH);
}

// Round 5
// 267.849 us; speedup vs baseline: 3.0084x; 1.0982x over previous
//
#include <hip/hip_runtime.h>

#define NB    16
#define NCH   512
#define NCOL  16384
#define NPTS  4096

// Barrier rule for bitonic passes, element mapping i ≡ tid (mod 1024):
//   j >= 1024 : pair is same-thread          -> no barrier
//   j <  64   : partner thread in same wave  -> no barrier (per-wave DS
//               ops are processed in order — HW-validated R3/R4, absmax 0)
//   else      : cross-wave -> __syncthreads(). Conservative lower edge 32.
#define PASS_SYNC(j) do { if ((j) >= 32 && (j) < 1024) __syncthreads(); } while (0)

// ---------------------------------------------------------------------------
// Phase 1: z[b][i] = max_c y[b][c][i] as 64-bit descending key:
//   key = (sortable_uint(z) << 32) | (16383 - i)   (unique -> total order;
//   desc sort == value desc, index asc == lax.top_k tie-breaking)
// ---------------------------------------------------------------------------
__global__ void max_key_kernel(const float* __restrict__ y,
                               unsigned long long* __restrict__ keys) {
    unsigned t = blockIdx.x * 256u + threadIdx.x;   // 0..4095 per batch
    unsigned b = blockIdx.y;
    unsigned i = t << 2;
    const float* p = y + ((size_t)b << 23) + i;
    float4 m = *(const float4*)p;
    #pragma unroll 8
    for (int c = 1; c < NCH; ++c) {
        float4 v = *(const float4*)(p + ((size_t)c << 14));
        m.x = fmaxf(m.x, v.x); m.y = fmaxf(m.y, v.y);
        m.z = fmaxf(m.z, v.z); m.w = fmaxf(m.w, v.w);
    }
    unsigned long long* kp = keys + ((size_t)b << 14) + i;
    float mv[4] = {m.x, m.y, m.z, m.w};
    #pragma unroll
    for (int q = 0; q < 4; ++q) {
        unsigned u = __float_as_uint(mv[q]);
        unsigned s = (u & 0x80000000u) ? ~u : (u | 0x80000000u);
        kp[q] = ((unsigned long long)s << 32) |
                (unsigned long long)(16383u - (i + q));
    }
}

// ---------------------------------------------------------------------------
// Phase 2a: sort each 2048-chunk descending (bitonic, LDS), in place.
// 8 chunks/batch x 16 batches = 128 blocks, 1024 threads (2 elems/thread).
// ---------------------------------------------------------------------------
__global__ __launch_bounds__(1024) void chunk_sort_kernel(
        unsigned long long* __restrict__ keys) {
    __shared__ unsigned long long sk[2048];   // 16 KiB
    unsigned tid = threadIdx.x;
    unsigned b = blockIdx.x >> 3, ch = blockIdx.x & 7;
    unsigned long long* gk = keys + ((size_t)b << 14) + ((size_t)ch << 11);

    sk[tid] = gk[tid];
    sk[tid + 1024] = gk[tid + 1024];
    __syncthreads();
    for (unsigned k = 2; k <= 2048; k <<= 1) {
        for (unsigned j = k >> 1; j > 0; j >>= 1) {
            PASS_SYNC(j);
            #pragma unroll
            for (unsigned s = 0; s < 2; ++s) {
                unsigned i = tid + (s << 10);
                unsigned ixj = i ^ j;
                if (ixj > i) {
                    unsigned long long a = sk[i], c2 = sk[ixj];
                    bool sw = ((i & k) == 0) ? (a < c2) : (a > c2);
                    if (sw) { sk[i] = c2; sk[ixj] = a; }
                }
            }
        }
    }
    __syncthreads();
    gk[tid] = sk[tid];
    gk[tid + 1024] = sk[tid + 1024];
}

// ---------------------------------------------------------------------------
// Phase 2b/c/d: merge-path merge of two sorted-desc lists A,B (length L each,
// at src + task*2L and + L), emitting the top NPTS of the merge, sorted desc.
// One block (256 thr) per task; each thread produces 16 outputs:
// lower-bound binary search on the diagonal, then sequential 2-way merge.
// All keys distinct -> strict compares, exact tie order. No barriers.
// If idx_out != nullptr, write decoded indices instead of keys.
// ---------------------------------------------------------------------------
__global__ __launch_bounds__(256) void merge_path_kernel(
        const unsigned long long* __restrict__ src,
        unsigned long long* __restrict__ dst,
        int* __restrict__ idx_out, unsigned L) {
    unsigned task = blockIdx.x;
    const unsigned long long* A = src + (size_t)task * (L << 1);
    const unsigned long long* B = A + L;
    unsigned p = threadIdx.x << 4;                 // first output position

    // lower-bound: smallest a in [lo,hi] with A[a] < B[p-1-a]
    unsigned lo = (p > L) ? (p - L) : 0u;
    unsigned hi = (p < L) ? p : L;
    while (lo < hi) {
        unsigned mid = (lo + hi) >> 1;
        if (A[mid] < B[p - 1 - mid]) hi = mid; else lo = mid + 1;
    }
    unsigned a = lo, b = p - lo;

    unsigned long long av = (a < L) ? A[a] : 0ull;
    unsigned long long bv = (b < L) ? B[b] : 0ull;
    #pragma unroll
    for (unsigned q = 0; q < 16; ++q) {
        bool ta = (b >= L) || (a < L && av > bv);
        unsigned long long o = ta ? av : bv;
        if (ta) { ++a; av = (a < L) ? A[a] : 0ull; }
        else    { ++b; bv = (b < L) ? B[b] : 0ull; }
        if (idx_out)
            idx_out[(size_t)task * NPTS + p + q] =
                (int)(16383u - (unsigned)(o & 0xFFFFFFFFull));
        else
            dst[(size_t)task * NPTS + p + q] = o;
    }
}

// ---------------------------------------------------------------------------
// Phase 3: LDS-staged row gather: 1024 thr + 64 KiB LDS -> 2 blocks/CU.
// Both global sides fully coalesced.
// ---------------------------------------------------------------------------
__global__ __launch_bounds__(1024) void row_gather_kernel(
        const float* __restrict__ src, const int* __restrict__ idx,
        float* __restrict__ out, int nch) {
    __shared__ float row[NCOL];   // 64 KiB
    unsigned bc = blockIdx.x;             // b*nch + c
    unsigned b  = bc / (unsigned)nch;
    const float4* sv = (const float4*)(src + ((size_t)bc << 14));
    float4* rv = (float4*)row;
    #pragma unroll
    for (unsigned i = threadIdx.x; i < NCOL / 4; i += 1024) rv[i] = sv[i];
    __syncthreads();
    const int* ib = idx + (b << 12);
    float* orow = out + (size_t)bc * NPTS;
    unsigned j = threadIdx.x << 2;
    int4 iv = *(const int4*)(ib + j);
    float4 ov;
    ov.x = row[iv.x]; ov.y = row[iv.y];
    ov.z = row[iv.z]; ov.w = row[iv.w];
    *(float4*)(orow + j) = ov;
}

extern "C" void kernel_launch(void* const* d_in, const int* in_sizes, int n_in,
                              void* d_out, int out_size, void* d_ws, size_t ws_size,
                              hipStream_t stream) {
    const float* x = (const float*)d_in[0];
    const float* y = (const float*)d_in[1];
    float* out = (float*)d_out;

    char* ws = (char*)d_ws;
    unsigned long long* keys  = (unsigned long long*)ws;               // 2 MiB
    unsigned long long* keys2 = (unsigned long long*)(ws + (2u << 20)); // 2 MiB
    int* idx = (int*)(ws + (4u << 20));                                // 256 KiB

    // 1) per-column channel max -> u64 keys
    max_key_kernel<<<dim3(NCOL / 4 / 256, NB), 256, 0, stream>>>(y, keys);
    // 2) sort 2048-chunks descending, in place (128 blocks)
    chunk_sort_kernel<<<NB * 8, 1024, 0, stream>>>(keys);
    // 3) merge tree via merge-path (exact truncation to top-4096 per level)
    //    L1: 64 tasks: (2048,2048) -> 4096         keys  -> keys2
    merge_path_kernel<<<NB * 4, 256, 0, stream>>>(keys, keys2, nullptr, 2048);
    //    L2: 32 tasks: top-4096 of (4096,4096)     keys2 -> keys
    merge_path_kernel<<<NB * 2, 256, 0, stream>>>(keys2, keys, nullptr, 4096);
    //    L3: 16 tasks: top-4096 of (4096,4096)     keys  -> idx (decoded)
    merge_path_kernel<<<NB, 256, 0, stream>>>(keys, nullptr, idx, 4096);
    // 4) gathers
    row_gather_kernel<<<NB * 3, 1024, 0, stream>>>(x, idx, out, 3);
    row_gather_kernel<<<NB * NCH, 1024, 0, stream>>>(
        y, idx, out + (size_t)NB * 3 * NPTS, NCH);
}